// Round 10
// baseline (58.356 us; speedup 1.0000x reference)
//
#include <hip/hip_runtime.h>

#define QDIM 21
#define NDIM 1368
#define OUTSTRIDE 64000

typedef __attribute__((ext_vector_type(4))) float f32x4;
typedef __attribute__((ext_vector_type(8))) short bf16x8s;
typedef __attribute__((ext_vector_type(4))) unsigned int u32x4;

typedef __attribute__((address_space(1))) const unsigned int* gas_p;
typedef __attribute__((address_space(3))) unsigned int* las_p;

static __device__ __forceinline__ void gload16(const float* g, char* l) {
    __builtin_amdgcn_global_load_lds((gas_p)(const void*)g, (las_p)(void*)l, 16, 0, 0);
}

// pack two f32 -> two bf16 (round-half-up) — proven in R5-R8
static __device__ __forceinline__ unsigned int pk2(float lo, float hi) {
    unsigned int a = __float_as_uint(lo) + 0x8000u;
    unsigned int b = __float_as_uint(hi) + 0x8000u;
    return __builtin_amdgcn_perm(b, a, 0x07060302);
}

static __device__ __forceinline__ bf16x8s pack8(f32x4 lo, f32x4 hi) {
    u32x4 p;
    p[0] = pk2(lo[0], lo[1]);
    p[1] = pk2(lo[2], lo[3]);
    p[2] = pk2(hi[0], hi[1]);
    p[3] = pk2(hi[2], hi[3]);
    return __builtin_bit_cast(bf16x8s, p);
}

// m204 bijective chunk swizzle within one filterbank's block range.
static __device__ __forceinline__ int chunk_swz(int idx, int n) {
    int xcd = idx & 7;
    int i   = idx >> 3;
    int q = n >> 3, r = n & 7;
    int base = (xcd < r) ? xcd * (q + 1) : r * (q + 1) + (xcd - r) * q;
    return base + i;
}

// One 2-wave block computes C[0:64, n0:n0+32] for position p.
//  - A (x window): PRIVATE per wave -> PLAIN compiler loads into named f32x4
//    regs, prefetched one tile ahead. Issue point pinned by the memory-clobber
//    asm at phase boundaries; compiler's waitcnt pass guarantees correctness
//    (it runs post-regalloc and covers allocator copies — the R9 failure).
//  - B (weights, shared): gload_lds ring, 3 stages x B[32][32]f32 = 12 KB.
//    XOR swizzle seg^(row&7) via pre-swizzled global source col.
//  - Phase t: vmcnt(6) [drains B(t); leaves A(t)? no: A(t) drained by
//    compiler's pack wait in phase t-1; leaves A(t+1)/B(t+2) issue window];
//    s_barrier; ds_read B(t); load A(t+1); STAGE B(t+2) -> slot (t-1)%3;
//    pack; 4 MFMA.
template<int WLOG2, int NTX, int D, int P, int S, int K>
__device__ __forceinline__ void fbk_body(const float* __restrict__ x,
                                         const float* __restrict__ W,
                                         float* __restrict__ out, int bid,
                                         char* lds) {
    constexpr int WWIN = 1 << WLOG2;
    constexpr int G = (K + 31) / 32;          // 42 / 21 / 11
    constexpr bool TAIL = (K % 32) != 0;      // fb0 only (K=336)
    constexpr int KREM = K % 32;              // 16 for fb0
    constexpr int FMAXC = (K - 4) & ~3;
    constexpr int ADV_EO = (WLOG2 == 6) ? 32 : ((32 >> WLOG2) * NDIM);
    constexpr int ADV_OE = (WLOG2 == 6) ? (NDIM - 32) : ((32 >> WLOG2) * NDIM);

    const int n0 = (bid % NTX) * 32;
    const int p  = bid / NTX;
    const int start = (p == P - 1) ? (NDIM - WWIN) : p * S;

    const int tid  = threadIdx.x;
    const int wid  = tid >> 6;                // 0..1
    const int lane = tid & 63;
    const int wm = wid * 32;                  // wave's private row range
    const int lr = lane & 15;
    const int hi = lane >> 4;
    const int kb = hi * 8;

    // ---- B staging constants (wave w stages rows w*16..+16 via 2 gload16)
    const int lrow = lane >> 3;
    const int g4   = ((lane & 7) ^ lrow) * 4;
    const float* Wp  = W + (size_t)(p * D + n0) * K;
    const float* wb0 = Wp + (size_t)(wid * 16 + lrow) * K;
    const float* wb1 = wb0 + (size_t)8 * K;
    char* ldsw = lds + wid * 2048;

    // ---- A pointers (per lane: rows wm+lr, wm+16+lr, 8 contiguous f32 @ kb)
    const int q0 = kb >> WLOG2;
    const int j0 = kb & (WWIN - 1);
    const float* pA0 = x + ((size_t)(wm + lr) * QDIM + q0) * NDIM + start + j0;
    const float* pA1 = pA0 + (size_t)16 * QDIM * NDIM;

    // ---- B fragment read offsets (swizzled)
    const int x7 = lr & 7;
    const int c0 = ((hi * 2)     ^ x7) * 16;
    const int c1 = ((hi * 2 + 1) ^ x7) * 16;
    const int oB0 = lr * 128;
    const int oB1 = (16 + lr) * 128;

    f32x4 acc[2][2] = {};

    auto STAGE = [&](int t, int sb) {
        int f = t * 32 + g4;
        if constexpr (TAIL) f = (f > FMAXC) ? FMAXC : f;  // garbage; A zeroed
        char* d = ldsw + sb;
        gload16(wb0 + f, d);
        gload16(wb1 + f, d + 1024);
    };

    // A prefetch register sets (named -> static indexing)
    f32x4 aA0l, aA0h, aA1l, aA1h;   // set A
    f32x4 aB0l, aB0h, aB1l, aB1h;   // set B

    // prologue: A(0) -> set A (plain loads); B(0)->slot0; B(1)->slot1
    aA0l = *(const f32x4*)pA0; aA0h = *(const f32x4*)(pA0 + 4);
    aA1l = *(const f32x4*)pA1; aA1h = *(const f32x4*)(pA1 + 4);
    pA0 += ADV_EO; pA1 += ADV_EO;
    STAGE(0, 0);
    STAGE(1, 4096);
    // drain B(0) in every legal ordering (keeps <=2 newest in flight)
    asm volatile("s_waitcnt vmcnt(2)" ::: "memory");

    int cs = 0;

#define PHASE(CURl0, CURh0, CURl1, CURh1, NXTl0, NXTh0, NXTl1, NXTh1, t, ADV) \
    {                                                                         \
        if ((t) == G - 1) { asm volatile("s_waitcnt vmcnt(4)" ::: "memory");} \
        else if ((t) > 0) { asm volatile("s_waitcnt vmcnt(6)" ::: "memory");} \
        __builtin_amdgcn_sched_barrier(0);                                    \
        __builtin_amdgcn_s_barrier();                                         \
        __builtin_amdgcn_sched_barrier(0);                                    \
        const char* sb_ = lds + cs;                                           \
        f32x4 b00 = *(const f32x4*)(sb_ + oB0 + c0);                          \
        f32x4 b01 = *(const f32x4*)(sb_ + oB0 + c1);                          \
        f32x4 b10 = *(const f32x4*)(sb_ + oB1 + c0);                          \
        f32x4 b11 = *(const f32x4*)(sb_ + oB1 + c1);                          \
        if ((t) + 1 < G) {                                                    \
            const float* q0p = pA0; const float* q1p = pA1;                   \
            if constexpr (TAIL) {                                             \
                if ((t) + 1 == G - 1 && kb >= KREM) { q0p = x; q1p = x; }     \
            }                                                                 \
            NXTl0 = *(const f32x4*)q0p; NXTh0 = *(const f32x4*)(q0p + 4);     \
            NXTl1 = *(const f32x4*)q1p; NXTh1 = *(const f32x4*)(q1p + 4);     \
            pA0 += (ADV); pA1 += (ADV);                                       \
        }                                                                     \
        if ((t) + 2 < G) {                                                    \
            int pb_ = (cs == 0) ? 8192 : cs - 4096;                           \
            STAGE((t) + 2, pb_);                                              \
        }                                                                     \
        __builtin_amdgcn_sched_barrier(0);                                    \
        f32x4 za0l = CURl0, za0h = CURh0, za1l = CURl1, za1h = CURh1;         \
        if constexpr (TAIL) {                                                 \
            if ((t) == G - 1 && kb >= KREM) {                                 \
                f32x4 z_ = {0.f, 0.f, 0.f, 0.f};                              \
                za0l = z_; za0h = z_; za1l = z_; za1h = z_;                   \
            }                                                                 \
        }                                                                     \
        bf16x8s A0 = pack8(za0l, za0h);                                       \
        bf16x8s A1 = pack8(za1l, za1h);                                       \
        bf16x8s B0 = pack8(b00, b01);                                         \
        bf16x8s B1 = pack8(b10, b11);                                         \
        acc[0][0] = __builtin_amdgcn_mfma_f32_16x16x32_bf16(A0, B0, acc[0][0], 0, 0, 0); \
        acc[0][1] = __builtin_amdgcn_mfma_f32_16x16x32_bf16(A0, B1, acc[0][1], 0, 0, 0); \
        acc[1][0] = __builtin_amdgcn_mfma_f32_16x16x32_bf16(A1, B0, acc[1][0], 0, 0, 0); \
        acc[1][1] = __builtin_amdgcn_mfma_f32_16x16x32_bf16(A1, B1, acc[1][1], 0, 0, 0); \
        cs = (cs == 8192) ? 0 : cs + 4096;                                    \
    }

    int t = 0;
    #pragma unroll 1
    for (; t + 1 < G; t += 2) {
        PHASE(aA0l, aA0h, aA1l, aA1h, aB0l, aB0h, aB1l, aB1h, t,     ADV_OE);
        PHASE(aB0l, aB0h, aB1l, aB1h, aA0l, aA0h, aA1l, aA1h, t + 1, ADV_EO);
    }
    if (t < G) {  // G odd: final phase, CUR = set A (loaded in prior odd phase)
        PHASE(aA0l, aA0h, aA1l, aA1h, aB0l, aB0h, aB1l, aB1h, t, ADV_OE);
    }
#undef PHASE

    // epilogue: C/D layout col = lane&15, row = (lane>>4)*4 + r
    const int colbase = p * D + n0;
    #pragma unroll
    for (int mi = 0; mi < 2; ++mi) {
        #pragma unroll
        for (int ni = 0; ni < 2; ++ni) {
            int col = colbase + ni * 16 + lr;
            int rbase = wm + mi * 16 + hi * 4;
            #pragma unroll
            for (int r = 0; r < 4; ++r) {
                out[(size_t)(rbase + r) * OUTSTRIDE + col] = acc[mi][ni][r];
            }
        }
    }
}

// 2000 blocks x 128 threads. Per-segment XCD chunk swizzle (balance+locality).
__global__ __launch_bounds__(128, 4)
void fbk_fused(const float* __restrict__ x,  const float* __restrict__ w0,
               const float* __restrict__ w1, const float* __restrict__ w2,
               float* __restrict__ out) {
    __shared__ __align__(16) char lds[12288];   // 3 stages x 4 KB (B only)
    const int pb = blockIdx.x;
    if (pb < 656) {
        // fb2: w=64, s=16, d=256, P=82, K=1344, 8 n-tiles of 32
        fbk_body<6, 8, 256, 82, 16, 1344>(x, w2, out + 43008, chunk_swz(pb, 656), lds);
    } else if (pb < 1324) {
        // fb1: w=32, s=8, d=128, P=167, K=672, 4 n-tiles of 32
        fbk_body<5, 4, 128, 167, 8, 672>(x, w1, out + 21632, chunk_swz(pb - 656, 668), lds);
    } else {
        // fb0: w=16, s=4, d=64, P=338, K=336, 2 n-tiles of 32
        fbk_body<4, 2, 64, 338, 4, 336>(x, w0, out, chunk_swz(pb - 1324, 676), lds);
    }
}

extern "C" void kernel_launch(void* const* d_in, const int* in_sizes, int n_in,
                              void* d_out, int out_size, void* d_ws, size_t ws_size,
                              hipStream_t stream) {
    const float* x  = (const float*)d_in[0];
    const float* w0 = (const float*)d_in[1];
    const float* w1 = (const float*)d_in[2];
    const float* w2 = (const float*)d_in[3];
    float* out = (float*)d_out;
    fbk_fused<<<dim3(2000), 128, 0, stream>>>(x, w0, w1, w2, out);
}

// Round 11
// 55.566 us; speedup vs baseline: 1.0502x; 1.0502x over previous
//
#include <hip/hip_runtime.h>

#define QDIM 21
#define NDIM 1368
#define OUTSTRIDE 64000

typedef __attribute__((ext_vector_type(4))) float f32x4;
typedef __attribute__((ext_vector_type(8))) short bf16x8s;
typedef __attribute__((ext_vector_type(4))) unsigned int u32x4;

// pack two f32 -> two bf16 (round-half-up) — proven R5-R8
static __device__ __forceinline__ unsigned int pk2(float lo, float hi) {
    unsigned int a = __float_as_uint(lo) + 0x8000u;
    unsigned int b = __float_as_uint(hi) + 0x8000u;
    return __builtin_amdgcn_perm(b, a, 0x07060302);
}

// m204 bijective chunk swizzle within one filterbank's block range.
static __device__ __forceinline__ int chunk_swz(int idx, int n) {
    int xcd = idx & 7;
    int i   = idx >> 3;
    int q = n >> 3, r = n & 7;
    int base = (xcd < r) ? xcd * (q + 1) : r * (q + 1) + (xcd - r) * q;
    return base + i;
}

// One 2-wave block computes C[0:64, n0:n0+32] for position p.
// bf16 ping-pong LDS: buffer = A[64 rows]@80B + B[32 rows]@80B = 7680 B, x2.
// (rows are 64B of bf16 data padded to 80B: bank-stride 20 -> 8-row period
//  covers all 32 banks -> conflict-free ds_read_b128 / ds_write_b128.)
// Register staging lives entirely WITHIN one loop iteration (load t+1 ->
// pack -> write), so no values cross the back-edge: nothing for regalloc to
// copy (R9 bug) and nothing for the scheduler to collapse (R3/R10 bug).
// Schedule: [loads t+1] SB0 [compute t: 4 ds_read + 4 MFMA] SB0
//           [auto-wait; pack; ds_write t+1 -> other buf] __syncthreads().
// Single barrier per tile is WAR-safe: reads of buf X in iter t-1 precede
// iter t-1's barrier; writes to buf X happen in iter t after that barrier.
template<int WLOG2, int NTX, int D, int P, int S, int K>
__device__ __forceinline__ void fbk_body(const float* __restrict__ x,
                                         const float* __restrict__ W,
                                         float* __restrict__ out, int bid,
                                         char* lds) {
    constexpr int WWIN = 1 << WLOG2;
    constexpr int G = (K + 31) / 32;          // 42 / 21 / 11
    constexpr bool TAIL = (K % 32) != 0;      // fb0 only (K=336)
    constexpr int ABYTES = 64 * 80;           // 5120
    constexpr int BUFB   = 7680;

    const int n0 = (bid % NTX) * 32;
    const int p  = bid / NTX;
    const int start = (p == P - 1) ? (NDIM - WWIN) : p * S;

    const int tid  = threadIdx.x;             // 0..127
    const int wid  = tid >> 6;                // 0..1
    const int lane = tid & 63;
    const int wm = wid * 32;                  // wave's output rows
    const int lr = lane & 15;
    const int hi = lane >> 4;                 // 0..3 (k-subgroup)

    // ---- staging coords: each thread stages 16 A-f32 + 8 B-f32 per tile
    const int arow = tid >> 1;                // 0..63 (batch row)
    const int ah   = tid & 1;                 // k-half (16 f32)
    const int brow = tid >> 2;                // 0..31 (n row)
    const int bq   = tid & 3;                 // k-quarter (8 f32)

    const float* xrow = x + (size_t)arow * QDIM * NDIM + start;
    const float* Wrow = W + (size_t)(p * D + n0 + brow) * K;

    char* wA = lds + arow * 80 + ah * 32;     // 2x ds_write_b128 (+0, +16)
    char* wB = lds + ABYTES + brow * 80 + bq * 16;

    // ---- fragment read offsets (A: m-row x k-seg; B: n-row x k-seg)
    const int rdA0 = (wm + lr) * 80 + hi * 16;
    const int rdA1 = (wm + 16 + lr) * 80 + hi * 16;
    const int rdB0 = ABYTES + lr * 80 + hi * 16;
    const int rdB1 = ABYTES + (16 + lr) * 80 + hi * 16;

    f32x4 acc[2][2] = {};
    f32x4 rA0, rA1, rA2, rA3, rB0, rB1;       // staging regs (intra-iteration)

    auto LOADT = [&](int t) {
        int fa = t * 32 + ah * 16;            // 16 consecutive k (never crosses q)
        int fb = t * 32 + bq * 8;
        if constexpr (TAIL) {
            if (fa >= K) fa = 0;              // safe addr; zeroed at pack
            if (fb >= K) fb = K - 8;          // in-bounds garbage; A=0 covers
        }
        int q = fa >> WLOG2;
        int j = fa & (WWIN - 1);
        const float* pa = xrow + q * NDIM + j;
        rA0 = *(const f32x4*)pa;
        rA1 = *(const f32x4*)(pa + 4);
        rA2 = *(const f32x4*)(pa + 8);
        rA3 = *(const f32x4*)(pa + 12);
        const float* pb = Wrow + fb;
        rB0 = *(const f32x4*)pb;
        rB1 = *(const f32x4*)(pb + 4);
    };

    auto PACKW = [&](int t, int dst) {
        bool zeroA = false;
        if constexpr (TAIL) zeroA = (t == G - 1) && (t * 32 + ah * 16 >= K);
        u32x4 pa0, pa1, pb;
        if (zeroA) {
            pa0 = (u32x4){0u, 0u, 0u, 0u};
            pa1 = (u32x4){0u, 0u, 0u, 0u};
        } else {
            pa0[0] = pk2(rA0[0], rA0[1]); pa0[1] = pk2(rA0[2], rA0[3]);
            pa0[2] = pk2(rA1[0], rA1[1]); pa0[3] = pk2(rA1[2], rA1[3]);
            pa1[0] = pk2(rA2[0], rA2[1]); pa1[1] = pk2(rA2[2], rA2[3]);
            pa1[2] = pk2(rA3[0], rA3[1]); pa1[3] = pk2(rA3[2], rA3[3]);
        }
        pb[0] = pk2(rB0[0], rB0[1]); pb[1] = pk2(rB0[2], rB0[3]);
        pb[2] = pk2(rB1[0], rB1[1]); pb[3] = pk2(rB1[2], rB1[3]);
        *(u32x4*)(wA + dst)      = pa0;
        *(u32x4*)(wA + dst + 16) = pa1;
        *(u32x4*)(wB + dst)      = pb;
    };

    auto COMPUTE = [&](int buf) {
        const char* b = lds + buf;
        bf16x8s a0 = *(const bf16x8s*)(b + rdA0);
        bf16x8s a1 = *(const bf16x8s*)(b + rdA1);
        bf16x8s b0 = *(const bf16x8s*)(b + rdB0);
        bf16x8s b1 = *(const bf16x8s*)(b + rdB1);
        acc[0][0] = __builtin_amdgcn_mfma_f32_16x16x32_bf16(a0, b0, acc[0][0], 0, 0, 0);
        acc[0][1] = __builtin_amdgcn_mfma_f32_16x16x32_bf16(a0, b1, acc[0][1], 0, 0, 0);
        acc[1][0] = __builtin_amdgcn_mfma_f32_16x16x32_bf16(a1, b0, acc[1][0], 0, 0, 0);
        acc[1][1] = __builtin_amdgcn_mfma_f32_16x16x32_bf16(a1, b1, acc[1][1], 0, 0, 0);
    };

    // prologue: tile 0 -> buf 0
    LOADT(0);
    PACKW(0, 0);
    __syncthreads();

    int cur = 0;
    #pragma unroll 1
    for (int t = 0; t < G; ++t) {
        if (t + 1 < G) LOADT(t + 1);
        __builtin_amdgcn_sched_barrier(0);
        COMPUTE(cur);
        __builtin_amdgcn_sched_barrier(0);
        if (t + 1 < G) {
            PACKW(t + 1, cur ^ BUFB);
            __syncthreads();
        }
        cur ^= BUFB;
    }

    // epilogue: C/D layout col = lane&15, row = (lane>>4)*4 + r
    const int colbase = p * D + n0;
    #pragma unroll
    for (int mi = 0; mi < 2; ++mi) {
        #pragma unroll
        for (int ni = 0; ni < 2; ++ni) {
            int col = colbase + ni * 16 + lr;
            int rbase = wm + mi * 16 + hi * 4;
            #pragma unroll
            for (int r = 0; r < 4; ++r) {
                out[(size_t)(rbase + r) * OUTSTRIDE + col] = acc[mi][ni][r];
            }
        }
    }
}

// 2000 blocks x 128 threads. Per-segment XCD chunk swizzle (balance+locality).
__global__ __launch_bounds__(128, 4)
void fbk_fused(const float* __restrict__ x,  const float* __restrict__ w0,
               const float* __restrict__ w1, const float* __restrict__ w2,
               float* __restrict__ out) {
    __shared__ __align__(16) char lds[2 * 7680];   // 15 KB ping-pong (bf16)
    const int pb = blockIdx.x;
    if (pb < 656) {
        // fb2: w=64, s=16, d=256, P=82, K=1344, 8 n-tiles of 32
        fbk_body<6, 8, 256, 82, 16, 1344>(x, w2, out + 43008, chunk_swz(pb, 656), lds);
    } else if (pb < 1324) {
        // fb1: w=32, s=8, d=128, P=167, K=672, 4 n-tiles of 32
        fbk_body<5, 4, 128, 167, 8, 672>(x, w1, out + 21632, chunk_swz(pb - 656, 668), lds);
    } else {
        // fb0: w=16, s=4, d=64, P=338, K=336, 2 n-tiles of 32
        fbk_body<4, 2, 64, 338, 4, 336>(x, w0, out, chunk_swz(pb - 1324, 676), lds);
    }
}

extern "C" void kernel_launch(void* const* d_in, const int* in_sizes, int n_in,
                              void* d_out, int out_size, void* d_ws, size_t ws_size,
                              hipStream_t stream) {
    const float* x  = (const float*)d_in[0];
    const float* w0 = (const float*)d_in[1];
    const float* w1 = (const float*)d_in[2];
    const float* w2 = (const float*)d_in[3];
    float* out = (float*)d_out;
    fbk_fused<<<dim3(2000), 128, 0, stream>>>(x, w0, w1, w2, out);
}

// Round 12
// 45.431 us; speedup vs baseline: 1.2845x; 1.2231x over previous
//
#include <hip/hip_runtime.h>

#define QDIM 21
#define NDIM 1368
#define OUTSTRIDE 64000

typedef __attribute__((ext_vector_type(4))) float f32x4;
typedef __attribute__((ext_vector_type(8))) short bf16x8s;
typedef __attribute__((ext_vector_type(4))) unsigned int u32x4;

typedef __attribute__((address_space(1))) const unsigned int* gas_p;
typedef __attribute__((address_space(3))) unsigned int* las_p;

static __device__ __forceinline__ void gload16(const float* g, char* l) {
    __builtin_amdgcn_global_load_lds((gas_p)(const void*)g, (las_p)(void*)l, 16, 0, 0);
}

// pack two f32 -> bf16x2 (round-half-up)
static __device__ __forceinline__ unsigned int pk2(float lo, float hi) {
    unsigned int a = __float_as_uint(lo) + 0x8000u;
    unsigned int b = __float_as_uint(hi) + 0x8000u;
    return __builtin_amdgcn_perm(b, a, 0x07060302);
}

static __device__ __forceinline__ bf16x8s pack8(f32x4 lo, f32x4 hi) {
    u32x4 p;
    p[0] = pk2(lo[0], lo[1]);
    p[1] = pk2(lo[2], lo[3]);
    p[2] = pk2(hi[0], hi[1]);
    p[3] = pk2(hi[2], hi[3]);
    return __builtin_bit_cast(bf16x8s, p);
}

// One 4-wave block computes C[0:64, n0:n0+64] for window position p.
// gload_lds ring pipeline: 3 stages x (A[64][32]f32 + B[64][32]f32) = 48 KB.
// Stage LDS row = 128 B = 8 segs of 16 B; XOR swizzle: LDS[r][s] holds global
// seg s^(r&7)  (loader fetches g=(l&7)^(l>>3); reader reads s=g^(r&7)).
// Per tile: waitcnt vmcnt(4); s_barrier; ds_read frags; pack; 4 MFMA;
// issue STAGE(t+2) into stage (t-1)%3 (reads of t-1 certified by this barrier).
// Body is byte-identical to R8 (41.7 us champion); only the grid map changed.
template<int WLOG2, int NTX, int D, int P, int S, int K>
__device__ __forceinline__ void fbk_body(const float* __restrict__ x,
                                         const float* __restrict__ W,
                                         float* __restrict__ out, int bid,
                                         char* ldsraw) {
    constexpr int WWIN = 1 << WLOG2;
    constexpr int G = (K + 31) / 32;          // 42 / 21 / 11
    constexpr bool TAIL = (K % 32) != 0;      // fb0 only (K=336)
    constexpr int FMAXC = (K - 4) & ~3;       // aligned clamp for tail loads

    const int n0 = (bid % NTX) * 64;
    const int p  = bid / NTX;
    const int start = (p == P - 1) ? (NDIM - WWIN) : p * S;

    const int tid  = threadIdx.x;
    const int wid  = tid >> 6;
    const int lane = tid & 63;
    const int wm = (wid >> 1) * 32;
    const int wn = (wid & 1) * 32;
    const int lr = lane & 15;
    const int hi = lane >> 4;
    const int kb = hi * 8;

    // ---- staging lane constants (per-wave: 2 A-insts + 2 B-insts, 8 rows each)
    const int lrow = lane >> 3;                   // row within instruction
    const int g4   = ((lane & 7) ^ lrow) * 4;     // inverse-swizzled source col (floats)
    const int r0   = 16 * wid + lrow;             // global row of inst 0
    const float* xb0 = x + (size_t)r0 * QDIM * NDIM + start;
    const float* Wp  = W + (size_t)(p * D + n0) * K;
    const float* wb0 = Wp + (size_t)r0 * K;
    const float* wb1 = wb0 + (size_t)8 * K;
    const int wA = 2048 * wid;                    // wave's A byte offset in stage

    auto STAGE = [&](int t, int sbase) {
        int f = t * 32 + g4;
        if constexpr (TAIL) f = (f > FMAXC) ? FMAXC : f;   // garbage, zeroed at read
        int q = f >> WLOG2;
        int j = f & (WWIN - 1);
        const float* ga = xb0 + q * NDIM + j;
        char* la = ldsraw + sbase + wA;
        char* lb = ldsraw + sbase + 8192 + wA;
        gload16(ga, la);
        gload16(ga + (size_t)8 * QDIM * NDIM, la + 1024);
        gload16(wb0 + f, lb);
        gload16(wb1 + f, lb + 1024);
    };

    // ---- fragment-read constants (swizzled): (wm|wn)+16 keeps r&7 == lr&7
    const int x7 = lr & 7;
    const int c0 = ((hi * 2)     ^ x7) * 16;
    const int c1 = ((hi * 2 + 1) ^ x7) * 16;
    const int oA0 = (wm + lr) * 128;
    const int oA1 = (wm + 16 + lr) * 128;
    const int oB0 = 8192 + (wn + lr) * 128;
    const int oB1 = 8192 + (wn + 16 + lr) * 128;

    f32x4 acc[2][2] = {};

    STAGE(0, 0);
    STAGE(1, 16384);

    int cs = 0;   // byte base of current tile's stage
    #pragma unroll 1
    for (int t = 0; t < G; ++t) {
        if (t + 1 < G) { asm volatile("s_waitcnt vmcnt(4)" ::: "memory"); }
        else           { asm volatile("s_waitcnt vmcnt(0)" ::: "memory"); }
        __builtin_amdgcn_sched_barrier(0);
        __builtin_amdgcn_s_barrier();
        __builtin_amdgcn_sched_barrier(0);

        const char* sb = ldsraw + cs;
        f32x4 a00 = *(const f32x4*)(sb + oA0 + c0);
        f32x4 a01 = *(const f32x4*)(sb + oA0 + c1);
        f32x4 a10 = *(const f32x4*)(sb + oA1 + c0);
        f32x4 a11 = *(const f32x4*)(sb + oA1 + c1);
        f32x4 b00 = *(const f32x4*)(sb + oB0 + c0);
        f32x4 b01 = *(const f32x4*)(sb + oB0 + c1);
        f32x4 b10 = *(const f32x4*)(sb + oB1 + c0);
        f32x4 b11 = *(const f32x4*)(sb + oB1 + c1);

        if constexpr (TAIL) {
            if (t == G - 1 && kb >= (K & 31)) {     // fully-invalid fragments
                f32x4 z = {0.f, 0.f, 0.f, 0.f};
                a00 = z; a01 = z; a10 = z; a11 = z;
            }
        }

        bf16x8s A0 = pack8(a00, a01);
        bf16x8s A1 = pack8(a10, a11);
        bf16x8s B0 = pack8(b00, b01);
        bf16x8s B1 = pack8(b10, b11);

        acc[0][0] = __builtin_amdgcn_mfma_f32_16x16x32_bf16(A0, B0, acc[0][0], 0, 0, 0);
        acc[0][1] = __builtin_amdgcn_mfma_f32_16x16x32_bf16(A0, B1, acc[0][1], 0, 0, 0);
        acc[1][0] = __builtin_amdgcn_mfma_f32_16x16x32_bf16(A1, B0, acc[1][0], 0, 0, 0);
        acc[1][1] = __builtin_amdgcn_mfma_f32_16x16x32_bf16(A1, B1, acc[1][1], 0, 0, 0);

        __builtin_amdgcn_sched_barrier(0);
        if (t + 2 < G) {
            int pb = (cs == 0) ? 32768 : cs - 16384;   // stage (t+2)%3 == (t-1)%3
            STAGE(t + 2, pb);
        }
        cs = (cs == 32768) ? 0 : cs + 16384;
    }

    // epilogue: C/D layout col = lane&15, row = (lane>>4)*4 + r
    const int colbase = p * D + n0;
    #pragma unroll
    for (int mi = 0; mi < 2; ++mi) {
        #pragma unroll
        for (int ni = 0; ni < 2; ++ni) {
            int col = colbase + wn + ni * 16 + lr;
            int rbase = wm + mi * 16 + hi * 4;
            #pragma unroll
            for (int r = 0; r < 4; ++r) {
                out[(size_t)(rbase + r) * OUTSTRIDE + col] = acc[mi][ni][r];
            }
        }
    }
}

// 1000 blocks. BALANCED PER-XCD SEGMENT INTERLEAVE:
//   physical XCD k = pb&7, local slot i = pb>>3 (0..124).
//   Slot i -> segment i%3 (0:fb2 1:fb1 2:fb0), segment-local rank r=i/3;
//   tail slots 123/124 complete fb1/fb0 chunks (exact bijection:
//   fb2 41/XCD; fb1 42 for k<6 else 41; fb0 42 for k<6 else 43).
//   Each XCD owns CONTIGUOUS rank chunks of every segment (keeps R8's
//   x-locality / FETCH=110MB) while every CU holds a fb2+fb1+fb0 MIX at all
//   times -> co-resident blocks with independent, staggered barrier schedules.
__global__ __launch_bounds__(256, 3)
void fbk_fused(const float* __restrict__ x,  const float* __restrict__ w0,
               const float* __restrict__ w1, const float* __restrict__ w2,
               float* __restrict__ out) {
    __shared__ __align__(16) char ldsraw[49152];   // 3 stages x 16 KB -> 3 blocks/CU
    const int k = blockIdx.x & 7;
    const int i = blockIdx.x >> 3;
    int seg, r;
    if (i < 123)      { seg = i % 3;              r = i / 3;  }
    else if (k < 6)   { seg = (i == 123) ? 1 : 2; r = 41;     }
    else              { seg = 2;                  r = i - 82; }   // 123->41, 124->42
    if (seg == 0) {
        // fb2: w=64, s=16, d=256, P=82, K=1344, 4 n-tiles; chunk start 41*k
        fbk_body<6, 4, 256, 82, 16, 1344>(x, w2, out + 43008, 41 * k + r, ldsraw);
    } else if (seg == 1) {
        // fb1: w=32, s=8, d=128, P=167, K=672, 2 n-tiles; starts 42k (k<7), 293 (k=7)
        int base = (k < 7) ? 42 * k : 293;
        fbk_body<5, 2, 128, 167, 8, 672>(x, w1, out + 21632, base + r, ldsraw);
    } else {
        // fb0: w=16, s=4, d=64, P=338, K=336, 1 n-tile; starts 42k (k<7), 295 (k=7)
        int base = (k < 7) ? 42 * k : 295;
        fbk_body<4, 1, 64, 338, 4, 336>(x, w0, out, base + r, ldsraw);
    }
}

extern "C" void kernel_launch(void* const* d_in, const int* in_sizes, int n_in,
                              void* d_out, int out_size, void* d_ws, size_t ws_size,
                              hipStream_t stream) {
    const float* x  = (const float*)d_in[0];
    const float* w0 = (const float*)d_in[1];
    const float* w1 = (const float*)d_in[2];
    const float* w2 = (const float*)d_in[3];
    float* out = (float*)d_out;
    fbk_fused<<<dim3(1000), 256, 0, stream>>>(x, w0, w1, w2, out);
}